// Round 10
// baseline (188.963 us; speedup 1.0000x reference)
//
#include <hip/hip_runtime.h>
#include <hip/hip_bf16.h>

typedef __attribute__((ext_vector_type(8))) short short8;
typedef __attribute__((ext_vector_type(4))) short svec4;
typedef __attribute__((ext_vector_type(4))) float float4_t;
typedef __attribute__((ext_vector_type(8))) _Float16 half8;

#define D_MODEL 1024
#define N_HEADS 16
#define HEAD_DIM 64
#define B_SZ 2
#define SEQ 2048
#define M_ROWS (B_SZ*SEQ)   // 4096
#define NQKV 3072
#define SC_LOG2E 0.18033688011112042f  // log2(e)/sqrt(HEAD_DIM)

__device__ __forceinline__ unsigned short f2bf(float f) {
  unsigned u = __float_as_uint(f);
  u += 0x7FFFu + ((u >> 16) & 1u);   // RNE
  return (unsigned short)(u >> 16);
}

__device__ __forceinline__ unsigned short f2h(float f) {
  _Float16 h = (_Float16)f;          // v_cvt_f16_f32, RNE
  return *(unsigned short*)&h;
}

// async global->LDS, 16B per lane. LDS base must be wave-uniform.
__device__ __forceinline__ void gl_lds16(const unsigned short* g, unsigned short* l) {
  __builtin_amdgcn_global_load_lds(
      (const __attribute__((address_space(1))) unsigned int*)(size_t)g,
      (__attribute__((address_space(3))) unsigned int*)(unsigned int)(size_t)l,
      16, 0, 0);
}

// ---- fused prep: x->bf16, Wp->bf16, Wq/Wk/Wv -> Wall [sel*1024+h*64+e][d] ----
__global__ void prep(const float* __restrict__ x, const float* __restrict__ Wp,
                     const float* __restrict__ Wq, const float* __restrict__ Wk,
                     const float* __restrict__ Wv,
                     unsigned short* __restrict__ xb, unsigned short* __restrict__ Wpb,
                     unsigned short* __restrict__ Wall) {
  __shared__ float t[16][17];
  int bid = blockIdx.x;
  if (bid < 5120) {
    const float* src; unsigned short* dst; int base;
    if (bid < 4096) { src = x;  dst = xb;  base = bid * 1024 + threadIdx.x * 4; }
    else            { src = Wp; dst = Wpb; base = (bid - 4096) * 1024 + threadIdx.x * 4; }
    float4 v = *(const float4*)(src + base);
    dst[base + 0] = f2bf(v.x);
    dst[base + 1] = f2bf(v.y);
    dst[base + 2] = f2bf(v.z);
    dst[base + 3] = f2bf(v.w);
  } else {
    int u = bid - 5120;
    int sel = u >> 12;
    u &= 4095;
    const float* W = sel == 0 ? Wq : (sel == 1 ? Wk : Wv);
    int d0 = (u & 63) * 16, e0 = ((u >> 6) & 3) * 16, hh = u >> 8;
    int tx = threadIdx.x & 15, ty = threadIdx.x >> 4;
    t[ty][tx] = W[hh * (D_MODEL * HEAD_DIM) + (d0 + ty) * HEAD_DIM + e0 + tx];
    __syncthreads();
    Wall[(size_t)(sel * 1024 + hh * 64 + e0 + ty) * D_MODEL + d0 + tx] = f2bf(t[tx][ty]);
  }
}

// ---- fused QKV, BK=64: halves barrier events vs BK=32 (32 MFMA/wave per
// 2-barrier step). [128][64] LDS tiles (32KB) with both-sides swizzle:
// pre-swizzled GLOBAL source col ((l&7)^(l>>3))*8 feeding linear gl_lds16
// dest; reads XOR the 8-short chunk index with (row&7). 41KB LDS total ->
// 3 blocks/CU. Epilogues unchanged. ----
__global__ __launch_bounds__(256) void qkv_gemm(const unsigned short* __restrict__ xb,
                                                const unsigned short* __restrict__ Wall,
                                                const float* __restrict__ bq,
                                                const float* __restrict__ bk,
                                                const float* __restrict__ bv,
                                                unsigned short* __restrict__ Qb,
                                                unsigned short* __restrict__ Kb,
                                                unsigned short* __restrict__ Vtb) {
  __shared__ unsigned short As[128 * 64], Bs[128 * 64];
  __shared__ __align__(16) unsigned short Stage[4][16 * 72];  // 1152 elem/wave
  const int m0 = blockIdx.x * 128, n0 = blockIdx.y * 128;
  const int lane = threadIdx.x & 63, w = threadIdx.x >> 6;
  const int l16 = lane & 15, quad = lane >> 4;
  const int wm = w & 1, wn = w >> 1;
  // staging: lane -> subrow sr = l>>3 (0..7), source col pre-swizzled
  const int sr = lane >> 3;
  const int scol = ((lane & 7) ^ sr) * 8;
  const unsigned short* gaA = xb + (size_t)(m0 + w * 32 + sr) * D_MODEL + scol;
  const unsigned short* gaB = Wall + (size_t)(n0 + w * 32 + sr) * D_MODEL + scol;
  unsigned short* lA = As + (w * 32) * 64;
  unsigned short* lB = Bs + (w * 32) * 64;
  const int rswz = (l16 & 7);                         // read-side chunk XOR
  float4_t acc[4][4];
  float4_t z = {0.f, 0.f, 0.f, 0.f};
#pragma unroll
  for (int i = 0; i < 4; i++)
#pragma unroll
    for (int j = 0; j < 4; j++) acc[i][j] = z;
  for (int k0 = 0; k0 < D_MODEL; k0 += 64) {
    __syncthreads();
#pragma unroll
    for (int j = 0; j < 4; j++) {
      gl_lds16(gaA + (size_t)j * 8 * D_MODEL + k0, lA + j * 8 * 64);
      gl_lds16(gaB + (size_t)j * 8 * D_MODEL + k0, lB + j * 8 * 64);
    }
    __syncthreads();
#pragma unroll
    for (int kk = 0; kk < 2; kk++) {
      const int ch = ((kk * 4 + quad) ^ rswz) * 8;
      short8 af[4], bf[4];
#pragma unroll
      for (int i = 0; i < 4; i++)
        af[i] = *(const short8*)&As[(wm * 64 + i * 16 + l16) * 64 + ch];
#pragma unroll
      for (int j = 0; j < 4; j++)
        bf[j] = *(const short8*)&Bs[(wn * 64 + j * 16 + l16) * 64 + ch];
#pragma unroll
      for (int i = 0; i < 4; i++)
#pragma unroll
        for (int j = 0; j < 4; j++)
          acc[i][j] = __builtin_amdgcn_mfma_f32_16x16x32_bf16(af[i], bf[j], acc[i][j], 0, 0, 0);
    }
  }
  const int nb = n0 + wn * 64;       // 64-aligned -> sel, h wave-uniform
  const int sel = nb >> 10;
  const int h = (nb >> 6) & 15;
  const float* bias = sel == 0 ? bq : (sel == 1 ? bk : bv);
  const int mbase = m0 + wm * 64;
  const int bb = mbase >> 11;
  const size_t bh = (size_t)(bb * N_HEADS + h);
  if (sel == 2) {
    // V: transpose 64x64 C-tile through wave-private LDS -> coalesced 16B stores (fp16)
    unsigned short* vs = &Stage[w][0];
    const size_t vbase = bh * (32 * 4096) + (size_t)((mbase >> 6) & 31) * 4096;
    const int e8 = lane >> 3, ch2 = lane & 7;
#pragma unroll
    for (int j = 0; j < 4; j++) {
      float be = bias[h * 64 + j * 16 + l16];
#pragma unroll
      for (int i = 0; i < 4; i++)
#pragma unroll
        for (int r = 0; r < 4; r++)
          vs[l16 * 72 + i * 16 + quad * 4 + r] = f2h(acc[i][j][r] + be);
      // wave-private, DS in-order: no barrier
#pragma unroll
      for (int rd = 0; rd < 2; rd++) {
        int er = rd * 8 + e8;
        short8 val = *(const short8*)(vs + er * 72 + ch2 * 8);
        *(short8*)(Vtb + vbase + (size_t)(j * 16 + er) * 64 + ch2 * 8) = val;
      }
    }
  } else {
    // Q/K: stage [s][e] j-slice (64x16, stride 18) in wave-private LDS -> b128 stores
    unsigned short* st = &Stage[w][0];
    unsigned short* dst = (sel == 0) ? Qb : Kb;
    const float qsc = (sel == 0) ? SC_LOG2E : 1.0f;
    const size_t rowbase = bh * SEQ + (mbase & (SEQ - 1));
    const int r2 = lane >> 1, c2 = lane & 1;
#pragma unroll
    for (int j = 0; j < 4; j++) {
      float be = bias[h * 64 + j * 16 + l16];
#pragma unroll
      for (int i = 0; i < 4; i++)
#pragma unroll
        for (int r = 0; r < 4; r++)
          st[(i * 16 + quad * 4 + r) * 18 + l16] = f2bf((acc[i][j][r] + be) * qsc);
#pragma unroll
      for (int p = 0; p < 2; p++) {
        int row = p * 32 + r2;
        short8 val = *(const short8*)(st + row * 18 + c2 * 8);
        *(short8*)(dst + (rowbase + row) * HEAD_DIM + j * 16 + c2 * 8) = val;
      }
    }
  }
}

// ---- flash attention v17 (R8-verified, ~45.4us): t-split, 64 q-rows/wave,
// swizzled unpadded K/V LDS, scalar f16 casts, LDS sum-combine. ----
__global__ __launch_bounds__(512) void attn_kernel(const unsigned short* __restrict__ Q,
                                                   const unsigned short* __restrict__ K,
                                                   const unsigned short* __restrict__ Vt,
                                                   unsigned short* __restrict__ concat) {
  __shared__ __align__(16) union ShU {
    unsigned short kv[2][4][64 * 64];                       // [grp][K0,K1,V0,V1] 64KB
    struct { float4_t ot[4][4][4][16][4]; float ls[4][4][16]; } c;  // 65KB combine
  } sh;
  const int b = blockIdx.z, h = blockIdx.y;
  const int tid = threadIdx.x;
  const int lane = tid & 63, w = tid >> 6;
  const int g = w >> 2, wq = w & 3;
  const int l16 = lane & 15, quad = lane >> 4;
  const size_t bh = (size_t)(b * N_HEADS + h);
  const int q0 = blockIdx.x * 256 + wq * 64;                // 64 q-rows per wave
  const int tb = g * 1024;                                  // this group's t-half base
  float4_t z = {0.f, 0.f, 0.f, 0.f};

  // Q B-frags: B[k=e][n=q], lane n=l16 (pre-scaled by log2e/8)
  short8 aq[4][2];
#pragma unroll
  for (int rg = 0; rg < 4; rg++)
#pragma unroll
    for (int hf = 0; hf < 2; hf++)
      aq[rg][hf] = *(const short8*)(Q + (bh * SEQ + q0 + rg * 16 + l16) * HEAD_DIM + hf * 32 + quad * 8);

  // staging: each group's 256 threads stage its own buffers
  const int tl = tid & 255;
  const int krow = tl >> 2, kch = (tl & 3) * 8;
  const unsigned short* kg = K + (bh * SEQ + tb + krow) * HEAD_DIM + kch;
  const int swz = (krow & 7) << 3;                          // write-side XOR (shorts)
  const int ktw0 = (krow * 64 + kch) ^ swz;
  const int ktw1 = (krow * 64 + kch + 32) ^ swz;
  // V staging: e-row = tl>>2, t-group vt0 = (tl&3)*16 (+8); perm t->t'
  const int vt0 = (tl & 3) * 16, vt1 = vt0 + 8;
  const unsigned short* vg = Vt + bh * (32 * 4096) + (size_t)(tb >> 6) * 4096 + krow * 64 + vt0;
  const int tp0 = ((vt0 >> 5) << 5) + (((vt0 >> 2) & 3) << 3) + (((vt0 >> 4) & 1) << 2);
  const int tp1 = ((vt1 >> 5) << 5) + (((vt1 >> 2) & 3) << 3) + (((vt1 >> 4) & 1) << 2);
  const int vtwA = (krow * 64 + tp0) ^ swz;
  const int vtwB = (krow * 64 + tp0 + 8) ^ swz;
  const int vtwC = (krow * 64 + tp1) ^ swz;
  const int vtwD = (krow * 64 + tp1 + 8) ^ swz;
  // read-side XOR (row & 7 == l16 & 7 for all frag rows)
  const int rsw = (l16 & 7) << 3;

  float4_t o[4][4];
#pragma unroll
  for (int rg = 0; rg < 4; rg++)
#pragma unroll
    for (int ne = 0; ne < 4; ne++) o[rg][ne] = z;
  float lsp[4] = {0.f, 0.f, 0.f, 0.f};

  short8 kreg0 = *(const short8*)kg;
  short8 kreg1 = *(const short8*)(kg + 32);
  short8 vreg0 = *(const short8*)vg;
  short8 vreg1 = *(const short8*)(vg + 8);
  kg += 4096; vg += 4096;

  auto step = [&](unsigned short* kb, unsigned short* vb, int itv) {
    *(short8*)(kb + ktw0) = kreg0;
    *(short8*)(kb + ktw1) = kreg1;
    // V: each 8-t chunk splits into two 4-t runs 8 apart in t'
    svec4 a0 = {vreg0[0], vreg0[1], vreg0[2], vreg0[3]};
    svec4 a1 = {vreg0[4], vreg0[5], vreg0[6], vreg0[7]};
    svec4 b0 = {vreg1[0], vreg1[1], vreg1[2], vreg1[3]};
    svec4 b1 = {vreg1[4], vreg1[5], vreg1[6], vreg1[7]};
    *(svec4*)(vb + vtwA) = a0;
    *(svec4*)(vb + vtwB) = a1;
    *(svec4*)(vb + vtwC) = b0;
    *(svec4*)(vb + vtwD) = b1;
    __syncthreads();
    if (itv < 15) {
      kreg0 = *(const short8*)kg;
      kreg1 = *(const short8*)(kg + 32);
      vreg0 = *(const short8*)vg;
      vreg1 = *(const short8*)(vg + 8);
      kg += 4096; vg += 4096;
    }
#pragma unroll
    for (int p = 0; p < 2; p++) {
      // QK for the pair's two 16-t tiles (kf shared across all 4 rg)
      float4_t s[2][4];  // [tcl][rg]
      __builtin_amdgcn_s_setprio(1);
#pragma unroll
      for (int tcl = 0; tcl < 2; tcl++) {
        int tc = 2 * p + tcl;
        short8 kf0 = *(const short8*)(kb + (((tc * 16 + l16) * 64 + quad * 8) ^ rsw));
        short8 kf1 = *(const short8*)(kb + (((tc * 16 + l16) * 64 + quad * 8 + 32) ^ rsw));
#pragma unroll
        for (int rg = 0; rg < 4; rg++) {
          s[tcl][rg] = __builtin_amdgcn_mfma_f32_16x16x32_bf16(kf0, aq[rg][0], z, 0, 0, 0);
          s[tcl][rg] = __builtin_amdgcn_mfma_f32_16x16x32_bf16(kf1, aq[rg][1], s[tcl][rg], 0, 0, 0);
        }
      }
      __builtin_amdgcn_s_setprio(0);
      // V B-frags (f16, k=quad*8+j over the pair's 32 t')
      half8 vf[4];
#pragma unroll
      for (int ne = 0; ne < 4; ne++)
        vf[ne] = *(const half8*)(vb + (((ne * 16 + l16) * 64 + p * 32 + quad * 8) ^ rsw));
#pragma unroll
      for (int rg = 0; rg < 4; rg++) {
        float pv[8];
#pragma unroll
        for (int r = 0; r < 4; r++) {
          pv[r]     = __builtin_amdgcn_exp2f(s[0][rg][r]);
          pv[4 + r] = __builtin_amdgcn_exp2f(s[1][rg][r]);
        }
        lsp[rg] += ((pv[0] + pv[1]) + (pv[2] + pv[3])) + ((pv[4] + pv[5]) + (pv[6] + pv[7]));
        half8 pa = {(_Float16)pv[0], (_Float16)pv[1], (_Float16)pv[2], (_Float16)pv[3],
                    (_Float16)pv[4], (_Float16)pv[5], (_Float16)pv[6], (_Float16)pv[7]};
        __builtin_amdgcn_s_setprio(1);
#pragma unroll
        for (int ne = 0; ne < 4; ne++)
          o[rg][ne] = __builtin_amdgcn_mfma_f32_16x16x32_f16(pa, vf[ne], o[rg][ne], 0, 0, 0);
        __builtin_amdgcn_s_setprio(0);
      }
    }
  };

  for (int it2 = 0; it2 < 8; ++it2) {
    step(sh.kv[g][0], sh.kv[g][2], 2 * it2);
    step(sh.kv[g][1], sh.kv[g][3], 2 * it2 + 1);
  }

  // row-sums over this t-half: lsp holds per-quad t-partials for q=l16
  float lsf[4];
#pragma unroll
  for (int rg = 0; rg < 4; rg++) {
    float v = lsp[rg];
    v += __shfl_xor(v, 16, 64);
    v += __shfl_xor(v, 32, 64);
    lsf[rg] = v;
  }

  __syncthreads();   // all K/V LDS reads done before union reuse
  if (g) {
#pragma unroll
    for (int rg = 0; rg < 4; rg++) {
#pragma unroll
      for (int ne = 0; ne < 4; ne++) sh.c.ot[wq][rg][ne][l16][quad] = o[rg][ne];
      if (quad == 0) sh.c.ls[wq][rg][l16] = lsf[rg];
    }
  }
  __syncthreads();
  if (!g) {
#pragma unroll
    for (int rg = 0; rg < 4; rg++) {
      float lt = lsf[rg] + sh.c.ls[wq][rg][l16];
#pragma unroll
      for (int ne = 0; ne < 4; ne++) {
        float4_t pp = sh.c.ot[wq][rg][ne][l16][quad];
        o[rg][ne] += pp;
      }
#pragma unroll
      for (int r = 0; r < 4; r++) {
        float li = 1.0f / __shfl(lt, quad * 4 + r, 64);
        int sr2 = q0 + rg * 16 + quad * 4 + r;
#pragma unroll
        for (int ne = 0; ne < 4; ne++)
          concat[((size_t)(b * SEQ + sr2)) * D_MODEL + h * 64 + ne * 16 + l16] = f2bf(o[rg][ne][r] * li);
      }
    }
  }
}

// ---- out = concat @ Wp^T + bp (f32 out): 128x128 tiles, BK=64 (same
// swizzled staging as qkv_gemm) -> 256 blocks. ----
__global__ __launch_bounds__(256) void out_gemm(const unsigned short* __restrict__ cb,
                                                const unsigned short* __restrict__ Wpb,
                                                const float* __restrict__ bp,
                                                float* __restrict__ out) {
  __shared__ unsigned short As[128 * 64], Bs[128 * 64];
  const int m0 = blockIdx.x * 128, n0 = blockIdx.y * 128;
  const int lane = threadIdx.x & 63, w = threadIdx.x >> 6;
  const int l16 = lane & 15, quad = lane >> 4;
  const int wm = w & 1, wn = w >> 1;
  const int sr = lane >> 3;
  const int scol = ((lane & 7) ^ sr) * 8;
  const unsigned short* gaA = cb + (size_t)(m0 + w * 32 + sr) * D_MODEL + scol;
  const unsigned short* gaB = Wpb + (size_t)(n0 + w * 32 + sr) * D_MODEL + scol;
  unsigned short* lA = As + (w * 32) * 64;
  unsigned short* lB = Bs + (w * 32) * 64;
  const int rswz = (l16 & 7);
  float4_t acc[4][4];
  float4_t z = {0.f, 0.f, 0.f, 0.f};
#pragma unroll
  for (int i = 0; i < 4; i++)
#pragma unroll
    for (int j = 0; j < 4; j++) acc[i][j] = z;
  for (int k0 = 0; k0 < D_MODEL; k0 += 64) {
    __syncthreads();
#pragma unroll
    for (int j = 0; j < 4; j++) {
      gl_lds16(gaA + (size_t)j * 8 * D_MODEL + k0, lA + j * 8 * 64);
      gl_lds16(gaB + (size_t)j * 8 * D_MODEL + k0, lB + j * 8 * 64);
    }
    __syncthreads();
#pragma unroll
    for (int kk = 0; kk < 2; kk++) {
      const int ch = ((kk * 4 + quad) ^ rswz) * 8;
      short8 af[4], bf[4];
#pragma unroll
      for (int i = 0; i < 4; i++)
        af[i] = *(const short8*)&As[(wm * 64 + i * 16 + l16) * 64 + ch];
#pragma unroll
      for (int j = 0; j < 4; j++)
        bf[j] = *(const short8*)&Bs[(wn * 64 + j * 16 + l16) * 64 + ch];
#pragma unroll
      for (int i = 0; i < 4; i++)
#pragma unroll
        for (int j = 0; j < 4; j++)
          acc[i][j] = __builtin_amdgcn_mfma_f32_16x16x32_bf16(af[i], bf[j], acc[i][j], 0, 0, 0);
    }
  }
#pragma unroll
  for (int i = 0; i < 4; i++)
#pragma unroll
    for (int j = 0; j < 4; j++)
#pragma unroll
      for (int r = 0; r < 4; r++) {
        int m = m0 + wm * 64 + i * 16 + quad * 4 + r;
        int oc = n0 + wn * 64 + j * 16 + l16;
        out[(size_t)m * D_MODEL + oc] = acc[i][j][r] + bp[oc];
      }
}

extern "C" void kernel_launch(void* const* d_in, const int* in_sizes, int n_in,
                              void* d_out, int out_size, void* d_ws, size_t ws_size,
                              hipStream_t stream) {
  const float* x  = (const float*)d_in[0];
  const float* Wq = (const float*)d_in[1];
  const float* Wk = (const float*)d_in[2];
  const float* Wv = (const float*)d_in[3];
  const float* bq = (const float*)d_in[4];
  const float* bk = (const float*)d_in[5];
  const float* bv = (const float*)d_in[6];
  const float* Wp = (const float*)d_in[7];
  const float* bp = (const float*)d_in[8];
  float* out = (float*)d_out;

  char* ws = (char*)d_ws;
  size_t off = 0;
  auto alloc = [&](size_t bytes) -> void* {
    void* p = ws + off;
    off += (bytes + 255) & ~(size_t)255;
    return p;
  };
  unsigned short* xb   = (unsigned short*)alloc((size_t)M_ROWS * D_MODEL * 2);
  unsigned short* Wall = (unsigned short*)alloc((size_t)NQKV * D_MODEL * 2);
  unsigned short* Wpb  = (unsigned short*)alloc((size_t)D_MODEL * D_MODEL * 2);
  unsigned short* Qb   = (unsigned short*)alloc((size_t)B_SZ * N_HEADS * SEQ * HEAD_DIM * 2);
  unsigned short* Kb   = (unsigned short*)alloc((size_t)B_SZ * N_HEADS * SEQ * HEAD_DIM * 2);
  unsigned short* Vtb  = (unsigned short*)alloc((size_t)B_SZ * N_HEADS * SEQ * HEAD_DIM * 2);
  unsigned short* cbuf = (unsigned short*)alloc((size_t)B_SZ * SEQ * D_MODEL * 2);

  prep<<<17408, 256, 0, stream>>>(x, Wp, Wq, Wk, Wv, xb, Wpb, Wall);

  qkv_gemm<<<dim3(M_ROWS / 128, NQKV / 128), 256, 0, stream>>>(xb, Wall, bq, bk, bv, Qb, Kb, Vtb);

  attn_kernel<<<dim3(SEQ / 256, N_HEADS, B_SZ), 512, 0, stream>>>(Qb, Kb, Vtb, cbuf);

  out_gemm<<<dim3(M_ROWS / 128, D_MODEL / 128), 256, 0, stream>>>(cbuf, Wpb, bp, out);
}

// Round 11
// 185.504 us; speedup vs baseline: 1.0186x; 1.0186x over previous
//
#include <hip/hip_runtime.h>
#include <hip/hip_bf16.h>

typedef __attribute__((ext_vector_type(8))) short short8;
typedef __attribute__((ext_vector_type(4))) short svec4;
typedef __attribute__((ext_vector_type(4))) float float4_t;
typedef __attribute__((ext_vector_type(8))) _Float16 half8;

#define D_MODEL 1024
#define N_HEADS 16
#define HEAD_DIM 64
#define B_SZ 2
#define SEQ 2048
#define M_ROWS (B_SZ*SEQ)   // 4096
#define NQKV 3072
#define SC_LOG2E 0.18033688011112042f  // log2(e)/sqrt(HEAD_DIM)

__device__ __forceinline__ unsigned short f2bf(float f) {
  unsigned u = __float_as_uint(f);
  u += 0x7FFFu + ((u >> 16) & 1u);   // RNE
  return (unsigned short)(u >> 16);
}

__device__ __forceinline__ unsigned short f2h(float f) {
  _Float16 h = (_Float16)f;          // v_cvt_f16_f32, RNE
  return *(unsigned short*)&h;
}

// async global->LDS, 16B per lane. LDS base must be wave-uniform.
__device__ __forceinline__ void gl_lds16(const unsigned short* g, unsigned short* l) {
  __builtin_amdgcn_global_load_lds(
      (const __attribute__((address_space(1))) unsigned int*)(size_t)g,
      (__attribute__((address_space(3))) unsigned int*)(unsigned int)(size_t)l,
      16, 0, 0);
}

// ---- fused prep: x->bf16, Wp->bf16, Wq/Wk/Wv -> Wall [sel*1024+h*64+e][d]
// Transpose part rewritten: 768 blocks of 64x64 f32 tiles through LDS
// (float4 loads, short8 stores) instead of 12288 scalar blocks. ----
__global__ void prep(const float* __restrict__ x, const float* __restrict__ Wp,
                     const float* __restrict__ Wq, const float* __restrict__ Wk,
                     const float* __restrict__ Wv,
                     unsigned short* __restrict__ xb, unsigned short* __restrict__ Wpb,
                     unsigned short* __restrict__ Wall) {
  __shared__ float ts[64][65];
  int bid = blockIdx.x;
  if (bid < 5120) {
    const float* src; unsigned short* dst; int base;
    if (bid < 4096) { src = x;  dst = xb;  base = bid * 1024 + threadIdx.x * 4; }
    else            { src = Wp; dst = Wpb; base = (bid - 4096) * 1024 + threadIdx.x * 4; }
    float4 v = *(const float4*)(src + base);
    dst[base + 0] = f2bf(v.x);
    dst[base + 1] = f2bf(v.y);
    dst[base + 2] = f2bf(v.z);
    dst[base + 3] = f2bf(v.w);
  } else {
    int u = bid - 5120;                 // 0..767
    int sel = u >> 8;                   // 256 blocks per sel (16 h x 16 d-tiles)
    int rem = u & 255;
    int hh = rem >> 4, dt = rem & 15;
    int d0 = dt * 64;
    const float* W = sel == 0 ? Wq : (sel == 1 ? Wk : Wv);
    // load 64x64 f32 tile: row = d-offset, col = e
    int ldr = threadIdx.x >> 2, ec = (threadIdx.x & 3) * 16;
    const float* src = W + (size_t)hh * (D_MODEL * HEAD_DIM) + (size_t)(d0 + ldr) * HEAD_DIM + ec;
#pragma unroll
    for (int j = 0; j < 4; j++) {
      float4 v = *(const float4*)(src + j * 4);
      ts[ldr][ec + j * 4 + 0] = v.x;
      ts[ldr][ec + j * 4 + 1] = v.y;
      ts[ldr][ec + j * 4 + 2] = v.z;
      ts[ldr][ec + j * 4 + 3] = v.w;
    }
    __syncthreads();
    // write Wall rows: n = sel*1024 + hh*64 + e, cols d0..d0+63 (bf16)
    int er = threadIdx.x >> 2, dc = (threadIdx.x & 3) * 16;
    short8 o0, o1;
#pragma unroll
    for (int j = 0; j < 8; j++) {
      o0[j] = (short)f2bf(ts[dc + j][er]);
      o1[j] = (short)f2bf(ts[dc + 8 + j][er]);
    }
    unsigned short* dst = Wall + (size_t)(sel * 1024 + hh * 64 + er) * D_MODEL + d0 + dc;
    *(short8*)dst = o0;
    *(short8*)(dst + 8) = o1;
  }
}

// ---- fused QKV, BK=64: [128][64] LDS tiles, both-sides swizzle, 32 MFMA
// per wave per 2-barrier step. Epilogues unchanged. ----
__global__ __launch_bounds__(256) void qkv_gemm(const unsigned short* __restrict__ xb,
                                                const unsigned short* __restrict__ Wall,
                                                const float* __restrict__ bq,
                                                const float* __restrict__ bk,
                                                const float* __restrict__ bv,
                                                unsigned short* __restrict__ Qb,
                                                unsigned short* __restrict__ Kb,
                                                unsigned short* __restrict__ Vtb) {
  __shared__ unsigned short As[128 * 64], Bs[128 * 64];
  __shared__ __align__(16) unsigned short Stage[4][16 * 72];  // 1152 elem/wave
  const int m0 = blockIdx.x * 128, n0 = blockIdx.y * 128;
  const int lane = threadIdx.x & 63, w = threadIdx.x >> 6;
  const int l16 = lane & 15, quad = lane >> 4;
  const int wm = w & 1, wn = w >> 1;
  // staging: lane -> subrow sr = l>>3 (0..7), source col pre-swizzled
  const int sr = lane >> 3;
  const int scol = ((lane & 7) ^ sr) * 8;
  const unsigned short* gaA = xb + (size_t)(m0 + w * 32 + sr) * D_MODEL + scol;
  const unsigned short* gaB = Wall + (size_t)(n0 + w * 32 + sr) * D_MODEL + scol;
  unsigned short* lA = As + (w * 32) * 64;
  unsigned short* lB = Bs + (w * 32) * 64;
  const int rswz = (l16 & 7);                         // read-side chunk XOR
  float4_t acc[4][4];
  float4_t z = {0.f, 0.f, 0.f, 0.f};
#pragma unroll
  for (int i = 0; i < 4; i++)
#pragma unroll
    for (int j = 0; j < 4; j++) acc[i][j] = z;
  for (int k0 = 0; k0 < D_MODEL; k0 += 64) {
    __syncthreads();
#pragma unroll
    for (int j = 0; j < 4; j++) {
      gl_lds16(gaA + (size_t)j * 8 * D_MODEL + k0, lA + j * 8 * 64);
      gl_lds16(gaB + (size_t)j * 8 * D_MODEL + k0, lB + j * 8 * 64);
    }
    __syncthreads();
#pragma unroll
    for (int kk = 0; kk < 2; kk++) {
      const int ch = ((kk * 4 + quad) ^ rswz) * 8;
      short8 af[4], bf[4];
#pragma unroll
      for (int i = 0; i < 4; i++)
        af[i] = *(const short8*)&As[(wm * 64 + i * 16 + l16) * 64 + ch];
#pragma unroll
      for (int j = 0; j < 4; j++)
        bf[j] = *(const short8*)&Bs[(wn * 64 + j * 16 + l16) * 64 + ch];
#pragma unroll
      for (int i = 0; i < 4; i++)
#pragma unroll
        for (int j = 0; j < 4; j++)
          acc[i][j] = __builtin_amdgcn_mfma_f32_16x16x32_bf16(af[i], bf[j], acc[i][j], 0, 0, 0);
    }
  }
  const int nb = n0 + wn * 64;       // 64-aligned -> sel, h wave-uniform
  const int sel = nb >> 10;
  const int h = (nb >> 6) & 15;
  const float* bias = sel == 0 ? bq : (sel == 1 ? bk : bv);
  const int mbase = m0 + wm * 64;
  const int bb = mbase >> 11;
  const size_t bh = (size_t)(bb * N_HEADS + h);
  if (sel == 2) {
    // V: transpose 64x64 C-tile through wave-private LDS -> coalesced 16B stores (fp16)
    unsigned short* vs = &Stage[w][0];
    const size_t vbase = bh * (32 * 4096) + (size_t)((mbase >> 6) & 31) * 4096;
    const int e8 = lane >> 3, ch2 = lane & 7;
#pragma unroll
    for (int j = 0; j < 4; j++) {
      float be = bias[h * 64 + j * 16 + l16];
#pragma unroll
      for (int i = 0; i < 4; i++)
#pragma unroll
        for (int r = 0; r < 4; r++)
          vs[l16 * 72 + i * 16 + quad * 4 + r] = f2h(acc[i][j][r] + be);
      // wave-private, DS in-order: no barrier
#pragma unroll
      for (int rd = 0; rd < 2; rd++) {
        int er = rd * 8 + e8;
        short8 val = *(const short8*)(vs + er * 72 + ch2 * 8);
        *(short8*)(Vtb + vbase + (size_t)(j * 16 + er) * 64 + ch2 * 8) = val;
      }
    }
  } else {
    // Q/K: stage [s][e] j-slice (64x16, stride 18) in wave-private LDS -> b128 stores
    unsigned short* st = &Stage[w][0];
    unsigned short* dst = (sel == 0) ? Qb : Kb;
    const float qsc = (sel == 0) ? SC_LOG2E : 1.0f;
    const size_t rowbase = bh * SEQ + (mbase & (SEQ - 1));
    const int r2 = lane >> 1, c2 = lane & 1;
#pragma unroll
    for (int j = 0; j < 4; j++) {
      float be = bias[h * 64 + j * 16 + l16];
#pragma unroll
      for (int i = 0; i < 4; i++)
#pragma unroll
        for (int r = 0; r < 4; r++)
          st[(i * 16 + quad * 4 + r) * 18 + l16] = f2bf((acc[i][j][r] + be) * qsc);
#pragma unroll
      for (int p = 0; p < 2; p++) {
        int row = p * 32 + r2;
        short8 val = *(const short8*)(st + row * 18 + c2 * 8);
        *(short8*)(dst + (rowbase + row) * HEAD_DIM + j * 16 + c2 * 8) = val;
      }
    }
  }
}

// ---- flash attention v18: v17 internals (t-split, 64 q-rows/wave, swizzled
// unpadded K/V LDS, LDS sum-combine) + XCD-AWARE DECODE (R3-proven): 256
// blocks = 8 XCD x 4 bh x 8 q-tiles -> same-bh blocks co-located per XCD,
// K/V L2-resident. Measured at this geometry: FETCH 71 -> ~12-13 MB. ----
__global__ __launch_bounds__(512) void attn_kernel(const unsigned short* __restrict__ Q,
                                                   const unsigned short* __restrict__ K,
                                                   const unsigned short* __restrict__ Vt,
                                                   unsigned short* __restrict__ concat) {
  __shared__ __align__(16) union ShU {
    unsigned short kv[2][4][64 * 64];                       // [grp][K0,K1,V0,V1] 64KB
    struct { float4_t ot[4][4][4][16][4]; float ls[4][4][16]; } c;  // 65KB combine
  } sh;
  // decode: 256 blocks = 8 XCD * (4 bh * 8 q-tiles)
  const int lin = blockIdx.x;
  const int xcd = lin & 7, slot = lin >> 3;                 // slot 0..31
  const int bh_i = xcd * 4 + (slot >> 3);
  const int b = bh_i >> 4, h = bh_i & 15;
  const int qt = slot & 7;
  const int tid = threadIdx.x;
  const int lane = tid & 63, w = tid >> 6;
  const int g = w >> 2, wq = w & 3;
  const int l16 = lane & 15, quad = lane >> 4;
  const size_t bh = (size_t)bh_i;
  const int q0 = qt * 256 + wq * 64;                        // 64 q-rows per wave
  const int tb = g * 1024;                                  // this group's t-half base
  float4_t z = {0.f, 0.f, 0.f, 0.f};

  // Q B-frags: B[k=e][n=q], lane n=l16 (pre-scaled by log2e/8)
  short8 aq[4][2];
#pragma unroll
  for (int rg = 0; rg < 4; rg++)
#pragma unroll
    for (int hf = 0; hf < 2; hf++)
      aq[rg][hf] = *(const short8*)(Q + (bh * SEQ + q0 + rg * 16 + l16) * HEAD_DIM + hf * 32 + quad * 8);

  // staging: each group's 256 threads stage its own buffers
  const int tl = tid & 255;
  const int krow = tl >> 2, kch = (tl & 3) * 8;
  const unsigned short* kg = K + (bh * SEQ + tb + krow) * HEAD_DIM + kch;
  const int swz = (krow & 7) << 3;                          // write-side XOR (shorts)
  const int ktw0 = (krow * 64 + kch) ^ swz;
  const int ktw1 = (krow * 64 + kch + 32) ^ swz;
  // V staging: e-row = tl>>2, t-group vt0 = (tl&3)*16 (+8); perm t->t'
  const int vt0 = (tl & 3) * 16, vt1 = vt0 + 8;
  const unsigned short* vg = Vt + bh * (32 * 4096) + (size_t)(tb >> 6) * 4096 + krow * 64 + vt0;
  const int tp0 = ((vt0 >> 5) << 5) + (((vt0 >> 2) & 3) << 3) + (((vt0 >> 4) & 1) << 2);
  const int tp1 = ((vt1 >> 5) << 5) + (((vt1 >> 2) & 3) << 3) + (((vt1 >> 4) & 1) << 2);
  const int vtwA = (krow * 64 + tp0) ^ swz;
  const int vtwB = (krow * 64 + tp0 + 8) ^ swz;
  const int vtwC = (krow * 64 + tp1) ^ swz;
  const int vtwD = (krow * 64 + tp1 + 8) ^ swz;
  // read-side XOR (row & 7 == l16 & 7 for all frag rows)
  const int rsw = (l16 & 7) << 3;

  float4_t o[4][4];
#pragma unroll
  for (int rg = 0; rg < 4; rg++)
#pragma unroll
    for (int ne = 0; ne < 4; ne++) o[rg][ne] = z;
  float lsp[4] = {0.f, 0.f, 0.f, 0.f};

  short8 kreg0 = *(const short8*)kg;
  short8 kreg1 = *(const short8*)(kg + 32);
  short8 vreg0 = *(const short8*)vg;
  short8 vreg1 = *(const short8*)(vg + 8);
  kg += 4096; vg += 4096;

  auto step = [&](unsigned short* kb, unsigned short* vb, int itv) {
    *(short8*)(kb + ktw0) = kreg0;
    *(short8*)(kb + ktw1) = kreg1;
    // V: each 8-t chunk splits into two 4-t runs 8 apart in t'
    svec4 a0 = {vreg0[0], vreg0[1], vreg0[2], vreg0[3]};
    svec4 a1 = {vreg0[4], vreg0[5], vreg0[6], vreg0[7]};
    svec4 b0 = {vreg1[0], vreg1[1], vreg1[2], vreg1[3]};
    svec4 b1 = {vreg1[4], vreg1[5], vreg1[6], vreg1[7]};
    *(svec4*)(vb + vtwA) = a0;
    *(svec4*)(vb + vtwB) = a1;
    *(svec4*)(vb + vtwC) = b0;
    *(svec4*)(vb + vtwD) = b1;
    __syncthreads();
    if (itv < 15) {
      kreg0 = *(const short8*)kg;
      kreg1 = *(const short8*)(kg + 32);
      vreg0 = *(const short8*)vg;
      vreg1 = *(const short8*)(vg + 8);
      kg += 4096; vg += 4096;
    }
#pragma unroll
    for (int p = 0; p < 2; p++) {
      // QK for the pair's two 16-t tiles (kf shared across all 4 rg)
      float4_t s[2][4];  // [tcl][rg]
      __builtin_amdgcn_s_setprio(1);
#pragma unroll
      for (int tcl = 0; tcl < 2; tcl++) {
        int tc = 2 * p + tcl;
        short8 kf0 = *(const short8*)(kb + (((tc * 16 + l16) * 64 + quad * 8) ^ rsw));
        short8 kf1 = *(const short8*)(kb + (((tc * 16 + l16) * 64 + quad * 8 + 32) ^ rsw));
#pragma unroll
        for (int rg = 0; rg < 4; rg++) {
          s[tcl][rg] = __builtin_amdgcn_mfma_f32_16x16x32_bf16(kf0, aq[rg][0], z, 0, 0, 0);
          s[tcl][rg] = __builtin_amdgcn_mfma_f32_16x16x32_bf16(kf1, aq[rg][1], s[tcl][rg], 0, 0, 0);
        }
      }
      __builtin_amdgcn_s_setprio(0);
      // V B-frags (f16, k=quad*8+j over the pair's 32 t')
      half8 vf[4];
#pragma unroll
      for (int ne = 0; ne < 4; ne++)
        vf[ne] = *(const half8*)(vb + (((ne * 16 + l16) * 64 + p * 32 + quad * 8) ^ rsw));
#pragma unroll
      for (int rg = 0; rg < 4; rg++) {
        float pv[8];
#pragma unroll
        for (int r = 0; r < 4; r++) {
          pv[r]     = __builtin_amdgcn_exp2f(s[0][rg][r]);
          pv[4 + r] = __builtin_amdgcn_exp2f(s[1][rg][r]);
        }
        lsp[rg] += ((pv[0] + pv[1]) + (pv[2] + pv[3])) + ((pv[4] + pv[5]) + (pv[6] + pv[7]));
        half8 pa = {(_Float16)pv[0], (_Float16)pv[1], (_Float16)pv[2], (_Float16)pv[3],
                    (_Float16)pv[4], (_Float16)pv[5], (_Float16)pv[6], (_Float16)pv[7]};
        __builtin_amdgcn_s_setprio(1);
#pragma unroll
        for (int ne = 0; ne < 4; ne++)
          o[rg][ne] = __builtin_amdgcn_mfma_f32_16x16x32_f16(pa, vf[ne], o[rg][ne], 0, 0, 0);
        __builtin_amdgcn_s_setprio(0);
      }
    }
  };

  for (int it2 = 0; it2 < 8; ++it2) {
    step(sh.kv[g][0], sh.kv[g][2], 2 * it2);
    step(sh.kv[g][1], sh.kv[g][3], 2 * it2 + 1);
  }

  // row-sums over this t-half: lsp holds per-quad t-partials for q=l16
  float lsf[4];
#pragma unroll
  for (int rg = 0; rg < 4; rg++) {
    float v = lsp[rg];
    v += __shfl_xor(v, 16, 64);
    v += __shfl_xor(v, 32, 64);
    lsf[rg] = v;
  }

  __syncthreads();   // all K/V LDS reads done before union reuse
  if (g) {
#pragma unroll
    for (int rg = 0; rg < 4; rg++) {
#pragma unroll
      for (int ne = 0; ne < 4; ne++) sh.c.ot[wq][rg][ne][l16][quad] = o[rg][ne];
      if (quad == 0) sh.c.ls[wq][rg][l16] = lsf[rg];
    }
  }
  __syncthreads();
  if (!g) {
#pragma unroll
    for (int rg = 0; rg < 4; rg++) {
      float lt = lsf[rg] + sh.c.ls[wq][rg][l16];
#pragma unroll
      for (int ne = 0; ne < 4; ne++) {
        float4_t pp = sh.c.ot[wq][rg][ne][l16][quad];
        o[rg][ne] += pp;
      }
#pragma unroll
      for (int r = 0; r < 4; r++) {
        float li = 1.0f / __shfl(lt, quad * 4 + r, 64);
        int sr2 = q0 + rg * 16 + quad * 4 + r;
#pragma unroll
        for (int ne = 0; ne < 4; ne++)
          concat[((size_t)(b * SEQ + sr2)) * D_MODEL + h * 64 + ne * 16 + l16] = f2bf(o[rg][ne][r] * li);
      }
    }
  }
}

// ---- out = concat @ Wp^T + bp (f32 out): 128x128 tiles, BK=64 (same
// swizzled staging as qkv_gemm) -> 256 blocks. ----
__global__ __launch_bounds__(256) void out_gemm(const unsigned short* __restrict__ cb,
                                                const unsigned short* __restrict__ Wpb,
                                                const float* __restrict__ bp,
                                                float* __restrict__ out) {
  __shared__ unsigned short As[128 * 64], Bs[128 * 64];
  const int m0 = blockIdx.x * 128, n0 = blockIdx.y * 128;
  const int lane = threadIdx.x & 63, w = threadIdx.x >> 6;
  const int l16 = lane & 15, quad = lane >> 4;
  const int wm = w & 1, wn = w >> 1;
  const int sr = lane >> 3;
  const int scol = ((lane & 7) ^ sr) * 8;
  const unsigned short* gaA = cb + (size_t)(m0 + w * 32 + sr) * D_MODEL + scol;
  const unsigned short* gaB = Wpb + (size_t)(n0 + w * 32 + sr) * D_MODEL + scol;
  unsigned short* lA = As + (w * 32) * 64;
  unsigned short* lB = Bs + (w * 32) * 64;
  const int rswz = (l16 & 7);
  float4_t acc[4][4];
  float4_t z = {0.f, 0.f, 0.f, 0.f};
#pragma unroll
  for (int i = 0; i < 4; i++)
#pragma unroll
    for (int j = 0; j < 4; j++) acc[i][j] = z;
  for (int k0 = 0; k0 < D_MODEL; k0 += 64) {
    __syncthreads();
#pragma unroll
    for (int j = 0; j < 4; j++) {
      gl_lds16(gaA + (size_t)j * 8 * D_MODEL + k0, lA + j * 8 * 64);
      gl_lds16(gaB + (size_t)j * 8 * D_MODEL + k0, lB + j * 8 * 64);
    }
    __syncthreads();
#pragma unroll
    for (int kk = 0; kk < 2; kk++) {
      const int ch = ((kk * 4 + quad) ^ rswz) * 8;
      short8 af[4], bf[4];
#pragma unroll
      for (int i = 0; i < 4; i++)
        af[i] = *(const short8*)&As[(wm * 64 + i * 16 + l16) * 64 + ch];
#pragma unroll
      for (int j = 0; j < 4; j++)
        bf[j] = *(const short8*)&Bs[(wn * 64 + j * 16 + l16) * 64 + ch];
#pragma unroll
      for (int i = 0; i < 4; i++)
#pragma unroll
        for (int j = 0; j < 4; j++)
          acc[i][j] = __builtin_amdgcn_mfma_f32_16x16x32_bf16(af[i], bf[j], acc[i][j], 0, 0, 0);
    }
  }
#pragma unroll
  for (int i = 0; i < 4; i++)
#pragma unroll
    for (int j = 0; j < 4; j++)
#pragma unroll
      for (int r = 0; r < 4; r++) {
        int m = m0 + wm * 64 + i * 16 + quad * 4 + r;
        int oc = n0 + wn * 64 + j * 16 + l16;
        out[(size_t)m * D_MODEL + oc] = acc[i][j][r] + bp[oc];
      }
}

extern "C" void kernel_launch(void* const* d_in, const int* in_sizes, int n_in,
                              void* d_out, int out_size, void* d_ws, size_t ws_size,
                              hipStream_t stream) {
  const float* x  = (const float*)d_in[0];
  const float* Wq = (const float*)d_in[1];
  const float* Wk = (const float*)d_in[2];
  const float* Wv = (const float*)d_in[3];
  const float* bq = (const float*)d_in[4];
  const float* bk = (const float*)d_in[5];
  const float* bv = (const float*)d_in[6];
  const float* Wp = (const float*)d_in[7];
  const float* bp = (const float*)d_in[8];
  float* out = (float*)d_out;

  char* ws = (char*)d_ws;
  size_t off = 0;
  auto alloc = [&](size_t bytes) -> void* {
    void* p = ws + off;
    off += (bytes + 255) & ~(size_t)255;
    return p;
  };
  unsigned short* xb   = (unsigned short*)alloc((size_t)M_ROWS * D_MODEL * 2);
  unsigned short* Wall = (unsigned short*)alloc((size_t)NQKV * D_MODEL * 2);
  unsigned short* Wpb  = (unsigned short*)alloc((size_t)D_MODEL * D_MODEL * 2);
  unsigned short* Qb   = (unsigned short*)alloc((size_t)B_SZ * N_HEADS * SEQ * HEAD_DIM * 2);
  unsigned short* Kb   = (unsigned short*)alloc((size_t)B_SZ * N_HEADS * SEQ * HEAD_DIM * 2);
  unsigned short* Vtb  = (unsigned short*)alloc((size_t)B_SZ * N_HEADS * SEQ * HEAD_DIM * 2);
  unsigned short* cbuf = (unsigned short*)alloc((size_t)B_SZ * SEQ * D_MODEL * 2);

  prep<<<5888, 256, 0, stream>>>(x, Wp, Wq, Wk, Wv, xb, Wpb, Wall);

  qkv_gemm<<<dim3(M_ROWS / 128, NQKV / 128), 256, 0, stream>>>(xb, Wall, bq, bk, bv, Qb, Kb, Vtb);

  attn_kernel<<<256, 512, 0, stream>>>(Qb, Kb, Vtb, cbuf);

  out_gemm<<<dim3(M_ROWS / 128, D_MODEL / 128), 256, 0, stream>>>(cbuf, Wpb, bp, out);
}

// Round 12
// 182.210 us; speedup vs baseline: 1.0371x; 1.0181x over previous
//
#include <hip/hip_runtime.h>
#include <hip/hip_bf16.h>

typedef __attribute__((ext_vector_type(8))) short short8;
typedef __attribute__((ext_vector_type(4))) short svec4;
typedef __attribute__((ext_vector_type(4))) float float4_t;
typedef __attribute__((ext_vector_type(8))) _Float16 half8;

#define D_MODEL 1024
#define N_HEADS 16
#define HEAD_DIM 64
#define B_SZ 2
#define SEQ 2048
#define M_ROWS (B_SZ*SEQ)   // 4096
#define NQKV 3072
#define SC_LOG2E 0.18033688011112042f  // log2(e)/sqrt(HEAD_DIM)

__device__ __forceinline__ unsigned short f2bf(float f) {
  unsigned u = __float_as_uint(f);
  u += 0x7FFFu + ((u >> 16) & 1u);   // RNE
  return (unsigned short)(u >> 16);
}

__device__ __forceinline__ unsigned short f2h(float f) {
  _Float16 h = (_Float16)f;          // v_cvt_f16_f32, RNE
  return *(unsigned short*)&h;
}

// async global->LDS, 16B per lane. LDS base must be wave-uniform.
__device__ __forceinline__ void gl_lds16(const unsigned short* g, unsigned short* l) {
  __builtin_amdgcn_global_load_lds(
      (const __attribute__((address_space(1))) unsigned int*)(size_t)g,
      (__attribute__((address_space(3))) unsigned int*)(unsigned int)(size_t)l,
      16, 0, 0);
}

// ---- fused prep: x->bf16, Wp->bf16, Wq/Wk/Wv -> Wall [sel*1024+h*64+e][d]
// Transpose part: 768 blocks of 64x64 f32 tiles through LDS. ----
__global__ void prep(const float* __restrict__ x, const float* __restrict__ Wp,
                     const float* __restrict__ Wq, const float* __restrict__ Wk,
                     const float* __restrict__ Wv,
                     unsigned short* __restrict__ xb, unsigned short* __restrict__ Wpb,
                     unsigned short* __restrict__ Wall) {
  __shared__ float ts[64][65];
  int bid = blockIdx.x;
  if (bid < 5120) {
    const float* src; unsigned short* dst; int base;
    if (bid < 4096) { src = x;  dst = xb;  base = bid * 1024 + threadIdx.x * 4; }
    else            { src = Wp; dst = Wpb; base = (bid - 4096) * 1024 + threadIdx.x * 4; }
    float4 v = *(const float4*)(src + base);
    dst[base + 0] = f2bf(v.x);
    dst[base + 1] = f2bf(v.y);
    dst[base + 2] = f2bf(v.z);
    dst[base + 3] = f2bf(v.w);
  } else {
    int u = bid - 5120;                 // 0..767
    int sel = u >> 8;                   // 256 blocks per sel (16 h x 16 d-tiles)
    int rem = u & 255;
    int hh = rem >> 4, dt = rem & 15;
    int d0 = dt * 64;
    const float* W = sel == 0 ? Wq : (sel == 1 ? Wk : Wv);
    // load 64x64 f32 tile: row = d-offset, col = e
    int ldr = threadIdx.x >> 2, ec = (threadIdx.x & 3) * 16;
    const float* src = W + (size_t)hh * (D_MODEL * HEAD_DIM) + (size_t)(d0 + ldr) * HEAD_DIM + ec;
#pragma unroll
    for (int j = 0; j < 4; j++) {
      float4 v = *(const float4*)(src + j * 4);
      ts[ldr][ec + j * 4 + 0] = v.x;
      ts[ldr][ec + j * 4 + 1] = v.y;
      ts[ldr][ec + j * 4 + 2] = v.z;
      ts[ldr][ec + j * 4 + 3] = v.w;
    }
    __syncthreads();
    // write Wall rows: n = sel*1024 + hh*64 + e, cols d0..d0+63 (bf16)
    int er = threadIdx.x >> 2, dc = (threadIdx.x & 3) * 16;
    short8 o0, o1;
#pragma unroll
    for (int j = 0; j < 8; j++) {
      o0[j] = (short)f2bf(ts[dc + j][er]);
      o1[j] = (short)f2bf(ts[dc + 8 + j][er]);
    }
    unsigned short* dst = Wall + (size_t)(sel * 1024 + hh * 64 + er) * D_MODEL + d0 + dc;
    *(short8*)dst = o0;
    *(short8*)(dst + 8) = o1;
  }
}

// ---- fused QKV, BK=64 DOUBLE-BUFFERED: prefetch tile t+1 before computing
// tile t -> the end-of-iteration barrier's implicit vmcnt(0) drains loads
// that had the whole 32-MFMA phase to land (latency hidden). ONE barrier per
// K-step. Both-sides swizzle as R9. 73KB LDS -> 2 blocks/CU (unchanged). ----
__global__ __launch_bounds__(256) void qkv_gemm(const unsigned short* __restrict__ xb,
                                                const unsigned short* __restrict__ Wall,
                                                const float* __restrict__ bq,
                                                const float* __restrict__ bk,
                                                const float* __restrict__ bv,
                                                unsigned short* __restrict__ Qb,
                                                unsigned short* __restrict__ Kb,
                                                unsigned short* __restrict__ Vtb) {
  __shared__ unsigned short As[2][128 * 64], Bs[2][128 * 64];
  __shared__ __align__(16) unsigned short Stage[4][16 * 72];  // 1152 elem/wave
  const int m0 = blockIdx.x * 128, n0 = blockIdx.y * 128;
  const int lane = threadIdx.x & 63, w = threadIdx.x >> 6;
  const int l16 = lane & 15, quad = lane >> 4;
  const int wm = w & 1, wn = w >> 1;
  // staging: lane -> subrow sr = l>>3 (0..7), source col pre-swizzled
  const int sr = lane >> 3;
  const int scol = ((lane & 7) ^ sr) * 8;
  const unsigned short* gaA = xb + (size_t)(m0 + w * 32 + sr) * D_MODEL + scol;
  const unsigned short* gaB = Wall + (size_t)(n0 + w * 32 + sr) * D_MODEL + scol;
  const int rswz = (l16 & 7);                         // read-side chunk XOR
  float4_t acc[4][4];
  float4_t z = {0.f, 0.f, 0.f, 0.f};
#pragma unroll
  for (int i = 0; i < 4; i++)
#pragma unroll
    for (int j = 0; j < 4; j++) acc[i][j] = z;

  auto stage = [&](int buf, int k0) {
#pragma unroll
    for (int j = 0; j < 4; j++) {
      gl_lds16(gaA + (size_t)j * 8 * D_MODEL + k0, &As[buf][(w * 32 + j * 8) * 64]);
      gl_lds16(gaB + (size_t)j * 8 * D_MODEL + k0, &Bs[buf][(w * 32 + j * 8) * 64]);
    }
  };

  stage(0, 0);
  __syncthreads();
  int cur = 0;
  for (int t = 0; t < 16; ++t) {
    if (t < 15) stage(cur ^ 1, (t + 1) * 64);
#pragma unroll
    for (int kk = 0; kk < 2; kk++) {
      const int ch = ((kk * 4 + quad) ^ rswz) * 8;
      short8 af[4], bf[4];
#pragma unroll
      for (int i = 0; i < 4; i++)
        af[i] = *(const short8*)&As[cur][(wm * 64 + i * 16 + l16) * 64 + ch];
#pragma unroll
      for (int j = 0; j < 4; j++)
        bf[j] = *(const short8*)&Bs[cur][(wn * 64 + j * 16 + l16) * 64 + ch];
#pragma unroll
      for (int i = 0; i < 4; i++)
#pragma unroll
        for (int j = 0; j < 4; j++)
          acc[i][j] = __builtin_amdgcn_mfma_f32_16x16x32_bf16(af[i], bf[j], acc[i][j], 0, 0, 0);
    }
    __syncthreads();
    cur ^= 1;
  }
  const int nb = n0 + wn * 64;       // 64-aligned -> sel, h wave-uniform
  const int sel = nb >> 10;
  const int h = (nb >> 6) & 15;
  const float* bias = sel == 0 ? bq : (sel == 1 ? bk : bv);
  const int mbase = m0 + wm * 64;
  const int bb = mbase >> 11;
  const size_t bh = (size_t)(bb * N_HEADS + h);
  if (sel == 2) {
    // V: transpose 64x64 C-tile through wave-private LDS -> coalesced 16B stores (fp16)
    unsigned short* vs = &Stage[w][0];
    const size_t vbase = bh * (32 * 4096) + (size_t)((mbase >> 6) & 31) * 4096;
    const int e8 = lane >> 3, ch2 = lane & 7;
#pragma unroll
    for (int j = 0; j < 4; j++) {
      float be = bias[h * 64 + j * 16 + l16];
#pragma unroll
      for (int i = 0; i < 4; i++)
#pragma unroll
        for (int r = 0; r < 4; r++)
          vs[l16 * 72 + i * 16 + quad * 4 + r] = f2h(acc[i][j][r] + be);
      // wave-private, DS in-order: no barrier
#pragma unroll
      for (int rd = 0; rd < 2; rd++) {
        int er = rd * 8 + e8;
        short8 val = *(const short8*)(vs + er * 72 + ch2 * 8);
        *(short8*)(Vtb + vbase + (size_t)(j * 16 + er) * 64 + ch2 * 8) = val;
      }
    }
  } else {
    // Q/K: stage [s][e] j-slice (64x16, stride 18) in wave-private LDS -> b128 stores
    unsigned short* st = &Stage[w][0];
    unsigned short* dst = (sel == 0) ? Qb : Kb;
    const float qsc = (sel == 0) ? SC_LOG2E : 1.0f;
    const size_t rowbase = bh * SEQ + (mbase & (SEQ - 1));
    const int r2 = lane >> 1, c2 = lane & 1;
#pragma unroll
    for (int j = 0; j < 4; j++) {
      float be = bias[h * 64 + j * 16 + l16];
#pragma unroll
      for (int i = 0; i < 4; i++)
#pragma unroll
        for (int r = 0; r < 4; r++)
          st[(i * 16 + quad * 4 + r) * 18 + l16] = f2bf((acc[i][j][r] + be) * qsc);
#pragma unroll
      for (int p = 0; p < 2; p++) {
        int row = p * 32 + r2;
        short8 val = *(const short8*)(st + row * 18 + c2 * 8);
        *(short8*)(dst + (rowbase + row) * HEAD_DIM + j * 16 + c2 * 8) = val;
      }
    }
  }
}

// ---- flash attention v18 (R10-verified, ~43us): t-split, 64 q-rows/wave,
// swizzled unpadded K/V LDS, LDS sum-combine, XCD-aware decode. ----
__global__ __launch_bounds__(512) void attn_kernel(const unsigned short* __restrict__ Q,
                                                   const unsigned short* __restrict__ K,
                                                   const unsigned short* __restrict__ Vt,
                                                   unsigned short* __restrict__ concat) {
  __shared__ __align__(16) union ShU {
    unsigned short kv[2][4][64 * 64];                       // [grp][K0,K1,V0,V1] 64KB
    struct { float4_t ot[4][4][4][16][4]; float ls[4][4][16]; } c;  // 65KB combine
  } sh;
  // decode: 256 blocks = 8 XCD * (4 bh * 8 q-tiles)
  const int lin = blockIdx.x;
  const int xcd = lin & 7, slot = lin >> 3;                 // slot 0..31
  const int bh_i = xcd * 4 + (slot >> 3);
  const int b = bh_i >> 4, h = bh_i & 15;
  const int qt = slot & 7;
  const int tid = threadIdx.x;
  const int lane = tid & 63, w = tid >> 6;
  const int g = w >> 2, wq = w & 3;
  const int l16 = lane & 15, quad = lane >> 4;
  const size_t bh = (size_t)bh_i;
  const int q0 = qt * 256 + wq * 64;                        // 64 q-rows per wave
  const int tb = g * 1024;                                  // this group's t-half base
  float4_t z = {0.f, 0.f, 0.f, 0.f};

  // Q B-frags: B[k=e][n=q], lane n=l16 (pre-scaled by log2e/8)
  short8 aq[4][2];
#pragma unroll
  for (int rg = 0; rg < 4; rg++)
#pragma unroll
    for (int hf = 0; hf < 2; hf++)
      aq[rg][hf] = *(const short8*)(Q + (bh * SEQ + q0 + rg * 16 + l16) * HEAD_DIM + hf * 32 + quad * 8);

  // staging: each group's 256 threads stage its own buffers
  const int tl = tid & 255;
  const int krow = tl >> 2, kch = (tl & 3) * 8;
  const unsigned short* kg = K + (bh * SEQ + tb + krow) * HEAD_DIM + kch;
  const int swz = (krow & 7) << 3;                          // write-side XOR (shorts)
  const int ktw0 = (krow * 64 + kch) ^ swz;
  const int ktw1 = (krow * 64 + kch + 32) ^ swz;
  // V staging: e-row = tl>>2, t-group vt0 = (tl&3)*16 (+8); perm t->t'
  const int vt0 = (tl & 3) * 16, vt1 = vt0 + 8;
  const unsigned short* vg = Vt + bh * (32 * 4096) + (size_t)(tb >> 6) * 4096 + krow * 64 + vt0;
  const int tp0 = ((vt0 >> 5) << 5) + (((vt0 >> 2) & 3) << 3) + (((vt0 >> 4) & 1) << 2);
  const int tp1 = ((vt1 >> 5) << 5) + (((vt1 >> 2) & 3) << 3) + (((vt1 >> 4) & 1) << 2);
  const int vtwA = (krow * 64 + tp0) ^ swz;
  const int vtwB = (krow * 64 + tp0 + 8) ^ swz;
  const int vtwC = (krow * 64 + tp1) ^ swz;
  const int vtwD = (krow * 64 + tp1 + 8) ^ swz;
  // read-side XOR (row & 7 == l16 & 7 for all frag rows)
  const int rsw = (l16 & 7) << 3;

  float4_t o[4][4];
#pragma unroll
  for (int rg = 0; rg < 4; rg++)
#pragma unroll
    for (int ne = 0; ne < 4; ne++) o[rg][ne] = z;
  float lsp[4] = {0.f, 0.f, 0.f, 0.f};

  short8 kreg0 = *(const short8*)kg;
  short8 kreg1 = *(const short8*)(kg + 32);
  short8 vreg0 = *(const short8*)vg;
  short8 vreg1 = *(const short8*)(vg + 8);
  kg += 4096; vg += 4096;

  auto step = [&](unsigned short* kb, unsigned short* vb, int itv) {
    *(short8*)(kb + ktw0) = kreg0;
    *(short8*)(kb + ktw1) = kreg1;
    // V: each 8-t chunk splits into two 4-t runs 8 apart in t'
    svec4 a0 = {vreg0[0], vreg0[1], vreg0[2], vreg0[3]};
    svec4 a1 = {vreg0[4], vreg0[5], vreg0[6], vreg0[7]};
    svec4 b0 = {vreg1[0], vreg1[1], vreg1[2], vreg1[3]};
    svec4 b1 = {vreg1[4], vreg1[5], vreg1[6], vreg1[7]};
    *(svec4*)(vb + vtwA) = a0;
    *(svec4*)(vb + vtwB) = a1;
    *(svec4*)(vb + vtwC) = b0;
    *(svec4*)(vb + vtwD) = b1;
    __syncthreads();
    if (itv < 15) {
      kreg0 = *(const short8*)kg;
      kreg1 = *(const short8*)(kg + 32);
      vreg0 = *(const short8*)vg;
      vreg1 = *(const short8*)(vg + 8);
      kg += 4096; vg += 4096;
    }
#pragma unroll
    for (int p = 0; p < 2; p++) {
      // QK for the pair's two 16-t tiles (kf shared across all 4 rg)
      float4_t s[2][4];  // [tcl][rg]
      __builtin_amdgcn_s_setprio(1);
#pragma unroll
      for (int tcl = 0; tcl < 2; tcl++) {
        int tc = 2 * p + tcl;
        short8 kf0 = *(const short8*)(kb + (((tc * 16 + l16) * 64 + quad * 8) ^ rsw));
        short8 kf1 = *(const short8*)(kb + (((tc * 16 + l16) * 64 + quad * 8 + 32) ^ rsw));
#pragma unroll
        for (int rg = 0; rg < 4; rg++) {
          s[tcl][rg] = __builtin_amdgcn_mfma_f32_16x16x32_bf16(kf0, aq[rg][0], z, 0, 0, 0);
          s[tcl][rg] = __builtin_amdgcn_mfma_f32_16x16x32_bf16(kf1, aq[rg][1], s[tcl][rg], 0, 0, 0);
        }
      }
      __builtin_amdgcn_s_setprio(0);
      // V B-frags (f16, k=quad*8+j over the pair's 32 t')
      half8 vf[4];
#pragma unroll
      for (int ne = 0; ne < 4; ne++)
        vf[ne] = *(const half8*)(vb + (((ne * 16 + l16) * 64 + p * 32 + quad * 8) ^ rsw));
#pragma unroll
      for (int rg = 0; rg < 4; rg++) {
        float pv[8];
#pragma unroll
        for (int r = 0; r < 4; r++) {
          pv[r]     = __builtin_amdgcn_exp2f(s[0][rg][r]);
          pv[4 + r] = __builtin_amdgcn_exp2f(s[1][rg][r]);
        }
        lsp[rg] += ((pv[0] + pv[1]) + (pv[2] + pv[3])) + ((pv[4] + pv[5]) + (pv[6] + pv[7]));
        half8 pa = {(_Float16)pv[0], (_Float16)pv[1], (_Float16)pv[2], (_Float16)pv[3],
                    (_Float16)pv[4], (_Float16)pv[5], (_Float16)pv[6], (_Float16)pv[7]};
        __builtin_amdgcn_s_setprio(1);
#pragma unroll
        for (int ne = 0; ne < 4; ne++)
          o[rg][ne] = __builtin_amdgcn_mfma_f32_16x16x32_f16(pa, vf[ne], o[rg][ne], 0, 0, 0);
        __builtin_amdgcn_s_setprio(0);
      }
    }
  };

  for (int it2 = 0; it2 < 8; ++it2) {
    step(sh.kv[g][0], sh.kv[g][2], 2 * it2);
    step(sh.kv[g][1], sh.kv[g][3], 2 * it2 + 1);
  }

  // row-sums over this t-half: lsp holds per-quad t-partials for q=l16
  float lsf[4];
#pragma unroll
  for (int rg = 0; rg < 4; rg++) {
    float v = lsp[rg];
    v += __shfl_xor(v, 16, 64);
    v += __shfl_xor(v, 32, 64);
    lsf[rg] = v;
  }

  __syncthreads();   // all K/V LDS reads done before union reuse
  if (g) {
#pragma unroll
    for (int rg = 0; rg < 4; rg++) {
#pragma unroll
      for (int ne = 0; ne < 4; ne++) sh.c.ot[wq][rg][ne][l16][quad] = o[rg][ne];
      if (quad == 0) sh.c.ls[wq][rg][l16] = lsf[rg];
    }
  }
  __syncthreads();
  if (!g) {
#pragma unroll
    for (int rg = 0; rg < 4; rg++) {
      float lt = lsf[rg] + sh.c.ls[wq][rg][l16];
#pragma unroll
      for (int ne = 0; ne < 4; ne++) {
        float4_t pp = sh.c.ot[wq][rg][ne][l16][quad];
        o[rg][ne] += pp;
      }
#pragma unroll
      for (int r = 0; r < 4; r++) {
        float li = 1.0f / __shfl(lt, quad * 4 + r, 64);
        int sr2 = q0 + rg * 16 + quad * 4 + r;
#pragma unroll
        for (int ne = 0; ne < 4; ne++)
          concat[((size_t)(b * SEQ + sr2)) * D_MODEL + h * 64 + ne * 16 + l16] = f2bf(o[rg][ne][r] * li);
      }
    }
  }
}

// ---- out = concat @ Wp^T + bp (f32 out): 128x128 tiles, BK=64,
// DOUBLE-BUFFERED (1 block/CU -> no TLP; dbuf hides the load latency). ----
__global__ __launch_bounds__(256) void out_gemm(const unsigned short* __restrict__ cb,
                                                const unsigned short* __restrict__ Wpb,
                                                const float* __restrict__ bp,
                                                float* __restrict__ out) {
  __shared__ unsigned short As[2][128 * 64], Bs[2][128 * 64];
  const int m0 = blockIdx.x * 128, n0 = blockIdx.y * 128;
  const int lane = threadIdx.x & 63, w = threadIdx.x >> 6;
  const int l16 = lane & 15, quad = lane >> 4;
  const int wm = w & 1, wn = w >> 1;
  const int sr = lane >> 3;
  const int scol = ((lane & 7) ^ sr) * 8;
  const unsigned short* gaA = cb + (size_t)(m0 + w * 32 + sr) * D_MODEL + scol;
  const unsigned short* gaB = Wpb + (size_t)(n0 + w * 32 + sr) * D_MODEL + scol;
  const int rswz = (l16 & 7);
  float4_t acc[4][4];
  float4_t z = {0.f, 0.f, 0.f, 0.f};
#pragma unroll
  for (int i = 0; i < 4; i++)
#pragma unroll
    for (int j = 0; j < 4; j++) acc[i][j] = z;

  auto stage = [&](int buf, int k0) {
#pragma unroll
    for (int j = 0; j < 4; j++) {
      gl_lds16(gaA + (size_t)j * 8 * D_MODEL + k0, &As[buf][(w * 32 + j * 8) * 64]);
      gl_lds16(gaB + (size_t)j * 8 * D_MODEL + k0, &Bs[buf][(w * 32 + j * 8) * 64]);
    }
  };

  stage(0, 0);
  __syncthreads();
  int cur = 0;
  for (int t = 0; t < 16; ++t) {
    if (t < 15) stage(cur ^ 1, (t + 1) * 64);
#pragma unroll
    for (int kk = 0; kk < 2; kk++) {
      const int ch = ((kk * 4 + quad) ^ rswz) * 8;
      short8 af[4], bf[4];
#pragma unroll
      for (int i = 0; i < 4; i++)
        af[i] = *(const short8*)&As[cur][(wm * 64 + i * 16 + l16) * 64 + ch];
#pragma unroll
      for (int j = 0; j < 4; j++)
        bf[j] = *(const short8*)&Bs[cur][(wn * 64 + j * 16 + l16) * 64 + ch];
#pragma unroll
      for (int i = 0; i < 4; i++)
#pragma unroll
        for (int j = 0; j < 4; j++)
          acc[i][j] = __builtin_amdgcn_mfma_f32_16x16x32_bf16(af[i], bf[j], acc[i][j], 0, 0, 0);
    }
    __syncthreads();
    cur ^= 1;
  }
#pragma unroll
  for (int i = 0; i < 4; i++)
#pragma unroll
    for (int j = 0; j < 4; j++)
#pragma unroll
      for (int r = 0; r < 4; r++) {
        int m = m0 + wm * 64 + i * 16 + quad * 4 + r;
        int oc = n0 + wn * 64 + j * 16 + l16;
        out[(size_t)m * D_MODEL + oc] = acc[i][j][r] + bp[oc];
      }
}

extern "C" void kernel_launch(void* const* d_in, const int* in_sizes, int n_in,
                              void* d_out, int out_size, void* d_ws, size_t ws_size,
                              hipStream_t stream) {
  const float* x  = (const float*)d_in[0];
  const float* Wq = (const float*)d_in[1];
  const float* Wk = (const float*)d_in[2];
  const float* Wv = (const float*)d_in[3];
  const float* bq = (const float*)d_in[4];
  const float* bk = (const float*)d_in[5];
  const float* bv = (const float*)d_in[6];
  const float* Wp = (const float*)d_in[7];
  const float* bp = (const float*)d_in[8];
  float* out = (float*)d_out;

  char* ws = (char*)d_ws;
  size_t off = 0;
  auto alloc = [&](size_t bytes) -> void* {
    void* p = ws + off;
    off += (bytes + 255) & ~(size_t)255;
    return p;
  };
  unsigned short* xb   = (unsigned short*)alloc((size_t)M_ROWS * D_MODEL * 2);
  unsigned short* Wall = (unsigned short*)alloc((size_t)NQKV * D_MODEL * 2);
  unsigned short* Wpb  = (unsigned short*)alloc((size_t)D_MODEL * D_MODEL * 2);
  unsigned short* Qb   = (unsigned short*)alloc((size_t)B_SZ * N_HEADS * SEQ * HEAD_DIM * 2);
  unsigned short* Kb   = (unsigned short*)alloc((size_t)B_SZ * N_HEADS * SEQ * HEAD_DIM * 2);
  unsigned short* Vtb  = (unsigned short*)alloc((size_t)B_SZ * N_HEADS * SEQ * HEAD_DIM * 2);
  unsigned short* cbuf = (unsigned short*)alloc((size_t)B_SZ * SEQ * D_MODEL * 2);

  prep<<<5888, 256, 0, stream>>>(x, Wp, Wq, Wk, Wv, xb, Wpb, Wall);

  qkv_gemm<<<dim3(M_ROWS / 128, NQKV / 128), 256, 0, stream>>>(xb, Wall, bq, bk, bv, Qb, Kb, Vtb);

  attn_kernel<<<256, 512, 0, stream>>>(Qb, Kb, Vtb, cbuf);

  out_gemm<<<dim3(M_ROWS / 128, D_MODEL / 128), 256, 0, stream>>>(cbuf, Wpb, bp, out);
}

// Round 13
// 175.568 us; speedup vs baseline: 1.0763x; 1.0378x over previous
//
#include <hip/hip_runtime.h>
#include <hip/hip_bf16.h>

typedef __attribute__((ext_vector_type(8))) short short8;
typedef __attribute__((ext_vector_type(4))) short svec4;
typedef __attribute__((ext_vector_type(4))) float float4_t;
typedef __attribute__((ext_vector_type(8))) _Float16 half8;

#define D_MODEL 1024
#define N_HEADS 16
#define HEAD_DIM 64
#define B_SZ 2
#define SEQ 2048
#define M_ROWS (B_SZ*SEQ)   // 4096
#define NQKV 3072
#define SC_LOG2E 0.18033688011112042f  // log2(e)/sqrt(HEAD_DIM)

__device__ __forceinline__ unsigned short f2bf(float f) {
  unsigned u = __float_as_uint(f);
  u += 0x7FFFu + ((u >> 16) & 1u);   // RNE
  return (unsigned short)(u >> 16);
}

__device__ __forceinline__ unsigned short f2h(float f) {
  _Float16 h = (_Float16)f;          // v_cvt_f16_f32, RNE
  return *(unsigned short*)&h;
}

// async global->LDS, 16B per lane. LDS base must be wave-uniform.
__device__ __forceinline__ void gl_lds16(const unsigned short* g, unsigned short* l) {
  __builtin_amdgcn_global_load_lds(
      (const __attribute__((address_space(1))) unsigned int*)(size_t)g,
      (__attribute__((address_space(3))) unsigned int*)(unsigned int)(size_t)l,
      16, 0, 0);
}

// ---- fused prep: x->bf16, Wp->bf16, Wq/Wk/Wv -> Wall [sel*1024+h*64+e][d]
// Transpose part: 768 blocks of 64x64 f32 tiles through LDS. ----
__global__ void prep(const float* __restrict__ x, const float* __restrict__ Wp,
                     const float* __restrict__ Wq, const float* __restrict__ Wk,
                     const float* __restrict__ Wv,
                     unsigned short* __restrict__ xb, unsigned short* __restrict__ Wpb,
                     unsigned short* __restrict__ Wall) {
  __shared__ float ts[64][65];
  int bid = blockIdx.x;
  if (bid < 5120) {
    const float* src; unsigned short* dst; int base;
    if (bid < 4096) { src = x;  dst = xb;  base = bid * 1024 + threadIdx.x * 4; }
    else            { src = Wp; dst = Wpb; base = (bid - 4096) * 1024 + threadIdx.x * 4; }
    float4 v = *(const float4*)(src + base);
    dst[base + 0] = f2bf(v.x);
    dst[base + 1] = f2bf(v.y);
    dst[base + 2] = f2bf(v.z);
    dst[base + 3] = f2bf(v.w);
  } else {
    int u = bid - 5120;                 // 0..767
    int sel = u >> 8;                   // 256 blocks per sel (16 h x 16 d-tiles)
    int rem = u & 255;
    int hh = rem >> 4, dt = rem & 15;
    int d0 = dt * 64;
    const float* W = sel == 0 ? Wq : (sel == 1 ? Wk : Wv);
    // load 64x64 f32 tile: row = d-offset, col = e
    int ldr = threadIdx.x >> 2, ec = (threadIdx.x & 3) * 16;
    const float* src = W + (size_t)hh * (D_MODEL * HEAD_DIM) + (size_t)(d0 + ldr) * HEAD_DIM + ec;
#pragma unroll
    for (int j = 0; j < 4; j++) {
      float4 v = *(const float4*)(src + j * 4);
      ts[ldr][ec + j * 4 + 0] = v.x;
      ts[ldr][ec + j * 4 + 1] = v.y;
      ts[ldr][ec + j * 4 + 2] = v.z;
      ts[ldr][ec + j * 4 + 3] = v.w;
    }
    __syncthreads();
    // write Wall rows: n = sel*1024 + hh*64 + e, cols d0..d0+63 (bf16)
    int er = threadIdx.x >> 2, dc = (threadIdx.x & 3) * 16;
    short8 o0, o1;
#pragma unroll
    for (int j = 0; j < 8; j++) {
      o0[j] = (short)f2bf(ts[dc + j][er]);
      o1[j] = (short)f2bf(ts[dc + 8 + j][er]);
    }
    unsigned short* dst = Wall + (size_t)(sel * 1024 + hh * 64 + er) * D_MODEL + d0 + dc;
    *(short8*)dst = o0;
    *(short8*)(dst + 8) = o1;
  }
}

// ---- fused QKV, BK=64 DOUBLE-BUFFERED (R11-verified): one barrier per
// K-step, prefetch t+1 before computing t. Both-sides swizzle. ----
__global__ __launch_bounds__(256) void qkv_gemm(const unsigned short* __restrict__ xb,
                                                const unsigned short* __restrict__ Wall,
                                                const float* __restrict__ bq,
                                                const float* __restrict__ bk,
                                                const float* __restrict__ bv,
                                                unsigned short* __restrict__ Qb,
                                                unsigned short* __restrict__ Kb,
                                                unsigned short* __restrict__ Vtb) {
  __shared__ unsigned short As[2][128 * 64], Bs[2][128 * 64];
  __shared__ __align__(16) unsigned short Stage[4][16 * 72];  // 1152 elem/wave
  const int m0 = blockIdx.x * 128, n0 = blockIdx.y * 128;
  const int lane = threadIdx.x & 63, w = threadIdx.x >> 6;
  const int l16 = lane & 15, quad = lane >> 4;
  const int wm = w & 1, wn = w >> 1;
  // staging: lane -> subrow sr = l>>3 (0..7), source col pre-swizzled
  const int sr = lane >> 3;
  const int scol = ((lane & 7) ^ sr) * 8;
  const unsigned short* gaA = xb + (size_t)(m0 + w * 32 + sr) * D_MODEL + scol;
  const unsigned short* gaB = Wall + (size_t)(n0 + w * 32 + sr) * D_MODEL + scol;
  const int rswz = (l16 & 7);                         // read-side chunk XOR
  float4_t acc[4][4];
  float4_t z = {0.f, 0.f, 0.f, 0.f};
#pragma unroll
  for (int i = 0; i < 4; i++)
#pragma unroll
    for (int j = 0; j < 4; j++) acc[i][j] = z;

  auto stage = [&](int buf, int k0) {
#pragma unroll
    for (int j = 0; j < 4; j++) {
      gl_lds16(gaA + (size_t)j * 8 * D_MODEL + k0, &As[buf][(w * 32 + j * 8) * 64]);
      gl_lds16(gaB + (size_t)j * 8 * D_MODEL + k0, &Bs[buf][(w * 32 + j * 8) * 64]);
    }
  };

  stage(0, 0);
  __syncthreads();
  int cur = 0;
  for (int t = 0; t < 16; ++t) {
    if (t < 15) stage(cur ^ 1, (t + 1) * 64);
#pragma unroll
    for (int kk = 0; kk < 2; kk++) {
      const int ch = ((kk * 4 + quad) ^ rswz) * 8;
      short8 af[4], bf[4];
#pragma unroll
      for (int i = 0; i < 4; i++)
        af[i] = *(const short8*)&As[cur][(wm * 64 + i * 16 + l16) * 64 + ch];
#pragma unroll
      for (int j = 0; j < 4; j++)
        bf[j] = *(const short8*)&Bs[cur][(wn * 64 + j * 16 + l16) * 64 + ch];
#pragma unroll
      for (int i = 0; i < 4; i++)
#pragma unroll
        for (int j = 0; j < 4; j++)
          acc[i][j] = __builtin_amdgcn_mfma_f32_16x16x32_bf16(af[i], bf[j], acc[i][j], 0, 0, 0);
    }
    __syncthreads();
    cur ^= 1;
  }
  const int nb = n0 + wn * 64;       // 64-aligned -> sel, h wave-uniform
  const int sel = nb >> 10;
  const int h = (nb >> 6) & 15;
  const float* bias = sel == 0 ? bq : (sel == 1 ? bk : bv);
  const int mbase = m0 + wm * 64;
  const int bb = mbase >> 11;
  const size_t bh = (size_t)(bb * N_HEADS + h);
  if (sel == 2) {
    // V: transpose 64x64 C-tile through wave-private LDS -> coalesced 16B stores (fp16)
    unsigned short* vs = &Stage[w][0];
    const size_t vbase = bh * (32 * 4096) + (size_t)((mbase >> 6) & 31) * 4096;
    const int e8 = lane >> 3, ch2 = lane & 7;
#pragma unroll
    for (int j = 0; j < 4; j++) {
      float be = bias[h * 64 + j * 16 + l16];
#pragma unroll
      for (int i = 0; i < 4; i++)
#pragma unroll
        for (int r = 0; r < 4; r++)
          vs[l16 * 72 + i * 16 + quad * 4 + r] = f2h(acc[i][j][r] + be);
      // wave-private, DS in-order: no barrier
#pragma unroll
      for (int rd = 0; rd < 2; rd++) {
        int er = rd * 8 + e8;
        short8 val = *(const short8*)(vs + er * 72 + ch2 * 8);
        *(short8*)(Vtb + vbase + (size_t)(j * 16 + er) * 64 + ch2 * 8) = val;
      }
    }
  } else {
    // Q/K: stage [s][e] j-slice (64x16, stride 18) in wave-private LDS -> b128 stores
    unsigned short* st = &Stage[w][0];
    unsigned short* dst = (sel == 0) ? Qb : Kb;
    const float qsc = (sel == 0) ? SC_LOG2E : 1.0f;
    const size_t rowbase = bh * SEQ + (mbase & (SEQ - 1));
    const int r2 = lane >> 1, c2 = lane & 1;
#pragma unroll
    for (int j = 0; j < 4; j++) {
      float be = bias[h * 64 + j * 16 + l16];
#pragma unroll
      for (int i = 0; i < 4; i++)
#pragma unroll
        for (int r = 0; r < 4; r++)
          st[(i * 16 + quad * 4 + r) * 18 + l16] = f2bf((acc[i][j][r] + be) * qsc);
#pragma unroll
      for (int p = 0; p < 2; p++) {
        int row = p * 32 + r2;
        short8 val = *(const short8*)(st + row * 18 + c2 * 8);
        *(short8*)(dst + (rowbase + row) * HEAD_DIM + j * 16 + c2 * 8) = val;
      }
    }
  }
}

// ---- flash attention v19: v18 + MFMA-ones row-sums. The 56 scalar lsp adds
// per step and all shfl reductions are replaced by one mfma(pa, ones) per
// (rg,p): lsacc[rg][r] accumulates the row-sum for q-row quad*4+r directly
// in the epilogue's register layout (no shfl needed). VALU -> MFMA pipe
// offload; +20 VGPR is free at 1 block/CU (grid=256). ----
__global__ __launch_bounds__(512) void attn_kernel(const unsigned short* __restrict__ Q,
                                                   const unsigned short* __restrict__ K,
                                                   const unsigned short* __restrict__ Vt,
                                                   unsigned short* __restrict__ concat) {
  __shared__ __align__(16) union ShU {
    unsigned short kv[2][4][64 * 64];                       // [grp][K0,K1,V0,V1] 64KB
    struct { float4_t ot[4][4][4][16][4]; float ls[4][4][16]; } c;  // 65KB combine
  } sh;
  // decode: 256 blocks = 8 XCD * (4 bh * 8 q-tiles)
  const int lin = blockIdx.x;
  const int xcd = lin & 7, slot = lin >> 3;                 // slot 0..31
  const int bh_i = xcd * 4 + (slot >> 3);
  const int b = bh_i >> 4, h = bh_i & 15;
  const int qt = slot & 7;
  const int tid = threadIdx.x;
  const int lane = tid & 63, w = tid >> 6;
  const int g = w >> 2, wq = w & 3;
  const int l16 = lane & 15, quad = lane >> 4;
  const size_t bh = (size_t)bh_i;
  const int q0 = qt * 256 + wq * 64;                        // 64 q-rows per wave
  const int tb = g * 1024;                                  // this group's t-half base
  float4_t z = {0.f, 0.f, 0.f, 0.f};
  const half8 vones = {(_Float16)1.f, (_Float16)1.f, (_Float16)1.f, (_Float16)1.f,
                       (_Float16)1.f, (_Float16)1.f, (_Float16)1.f, (_Float16)1.f};

  // Q B-frags: B[k=e][n=q], lane n=l16 (pre-scaled by log2e/8)
  short8 aq[4][2];
#pragma unroll
  for (int rg = 0; rg < 4; rg++)
#pragma unroll
    for (int hf = 0; hf < 2; hf++)
      aq[rg][hf] = *(const short8*)(Q + (bh * SEQ + q0 + rg * 16 + l16) * HEAD_DIM + hf * 32 + quad * 8);

  // staging: each group's 256 threads stage its own buffers
  const int tl = tid & 255;
  const int krow = tl >> 2, kch = (tl & 3) * 8;
  const unsigned short* kg = K + (bh * SEQ + tb + krow) * HEAD_DIM + kch;
  const int swz = (krow & 7) << 3;                          // write-side XOR (shorts)
  const int ktw0 = (krow * 64 + kch) ^ swz;
  const int ktw1 = (krow * 64 + kch + 32) ^ swz;
  // V staging: e-row = tl>>2, t-group vt0 = (tl&3)*16 (+8); perm t->t'
  const int vt0 = (tl & 3) * 16, vt1 = vt0 + 8;
  const unsigned short* vg = Vt + bh * (32 * 4096) + (size_t)(tb >> 6) * 4096 + krow * 64 + vt0;
  const int tp0 = ((vt0 >> 5) << 5) + (((vt0 >> 2) & 3) << 3) + (((vt0 >> 4) & 1) << 2);
  const int tp1 = ((vt1 >> 5) << 5) + (((vt1 >> 2) & 3) << 3) + (((vt1 >> 4) & 1) << 2);
  const int vtwA = (krow * 64 + tp0) ^ swz;
  const int vtwB = (krow * 64 + tp0 + 8) ^ swz;
  const int vtwC = (krow * 64 + tp1) ^ swz;
  const int vtwD = (krow * 64 + tp1 + 8) ^ swz;
  // read-side XOR (row & 7 == l16 & 7 for all frag rows)
  const int rsw = (l16 & 7) << 3;

  float4_t o[4][4];
#pragma unroll
  for (int rg = 0; rg < 4; rg++)
#pragma unroll
    for (int ne = 0; ne < 4; ne++) o[rg][ne] = z;
  float4_t lsacc[4];
#pragma unroll
  for (int rg = 0; rg < 4; rg++) lsacc[rg] = z;

  short8 kreg0 = *(const short8*)kg;
  short8 kreg1 = *(const short8*)(kg + 32);
  short8 vreg0 = *(const short8*)vg;
  short8 vreg1 = *(const short8*)(vg + 8);
  kg += 4096; vg += 4096;

  auto step = [&](unsigned short* kb, unsigned short* vb, int itv) {
    *(short8*)(kb + ktw0) = kreg0;
    *(short8*)(kb + ktw1) = kreg1;
    // V: each 8-t chunk splits into two 4-t runs 8 apart in t'
    svec4 a0 = {vreg0[0], vreg0[1], vreg0[2], vreg0[3]};
    svec4 a1 = {vreg0[4], vreg0[5], vreg0[6], vreg0[7]};
    svec4 b0 = {vreg1[0], vreg1[1], vreg1[2], vreg1[3]};
    svec4 b1 = {vreg1[4], vreg1[5], vreg1[6], vreg1[7]};
    *(svec4*)(vb + vtwA) = a0;
    *(svec4*)(vb + vtwB) = a1;
    *(svec4*)(vb + vtwC) = b0;
    *(svec4*)(vb + vtwD) = b1;
    __syncthreads();
    if (itv < 15) {
      kreg0 = *(const short8*)kg;
      kreg1 = *(const short8*)(kg + 32);
      vreg0 = *(const short8*)vg;
      vreg1 = *(const short8*)(vg + 8);
      kg += 4096; vg += 4096;
    }
#pragma unroll
    for (int p = 0; p < 2; p++) {
      // QK for the pair's two 16-t tiles (kf shared across all 4 rg)
      float4_t s[2][4];  // [tcl][rg]
      __builtin_amdgcn_s_setprio(1);
#pragma unroll
      for (int tcl = 0; tcl < 2; tcl++) {
        int tc = 2 * p + tcl;
        short8 kf0 = *(const short8*)(kb + (((tc * 16 + l16) * 64 + quad * 8) ^ rsw));
        short8 kf1 = *(const short8*)(kb + (((tc * 16 + l16) * 64 + quad * 8 + 32) ^ rsw));
#pragma unroll
        for (int rg = 0; rg < 4; rg++) {
          s[tcl][rg] = __builtin_amdgcn_mfma_f32_16x16x32_bf16(kf0, aq[rg][0], z, 0, 0, 0);
          s[tcl][rg] = __builtin_amdgcn_mfma_f32_16x16x32_bf16(kf1, aq[rg][1], s[tcl][rg], 0, 0, 0);
        }
      }
      __builtin_amdgcn_s_setprio(0);
      // V B-frags (f16, k=quad*8+j over the pair's 32 t')
      half8 vf[4];
#pragma unroll
      for (int ne = 0; ne < 4; ne++)
        vf[ne] = *(const half8*)(vb + (((ne * 16 + l16) * 64 + p * 32 + quad * 8) ^ rsw));
#pragma unroll
      for (int rg = 0; rg < 4; rg++) {
        float pv[8];
#pragma unroll
        for (int r = 0; r < 4; r++) {
          pv[r]     = __builtin_amdgcn_exp2f(s[0][rg][r]);
          pv[4 + r] = __builtin_amdgcn_exp2f(s[1][rg][r]);
        }
        half8 pa = {(_Float16)pv[0], (_Float16)pv[1], (_Float16)pv[2], (_Float16)pv[3],
                    (_Float16)pv[4], (_Float16)pv[5], (_Float16)pv[6], (_Float16)pv[7]};
        __builtin_amdgcn_s_setprio(1);
#pragma unroll
        for (int ne = 0; ne < 4; ne++)
          o[rg][ne] = __builtin_amdgcn_mfma_f32_16x16x32_f16(pa, vf[ne], o[rg][ne], 0, 0, 0);
        lsacc[rg] = __builtin_amdgcn_mfma_f32_16x16x32_f16(pa, vones, lsacc[rg], 0, 0, 0);
        __builtin_amdgcn_s_setprio(0);
      }
    }
  };

  for (int it2 = 0; it2 < 8; ++it2) {
    step(sh.kv[g][0], sh.kv[g][2], 2 * it2);
    step(sh.kv[g][1], sh.kv[g][3], 2 * it2 + 1);
  }

  __syncthreads();   // all K/V LDS reads done before union reuse
  if (g) {
#pragma unroll
    for (int rg = 0; rg < 4; rg++) {
#pragma unroll
      for (int ne = 0; ne < 4; ne++) sh.c.ot[wq][rg][ne][l16][quad] = o[rg][ne];
      if (l16 == 0) {
#pragma unroll
        for (int r = 0; r < 4; r++) sh.c.ls[wq][rg][quad * 4 + r] = lsacc[rg][r];
      }
    }
  }
  __syncthreads();
  if (!g) {
#pragma unroll
    for (int rg = 0; rg < 4; rg++) {
#pragma unroll
      for (int ne = 0; ne < 4; ne++) {
        float4_t pp = sh.c.ot[wq][rg][ne][l16][quad];
        o[rg][ne] += pp;
      }
#pragma unroll
      for (int r = 0; r < 4; r++) {
        float lt = lsacc[rg][r] + sh.c.ls[wq][rg][quad * 4 + r];
        float li = 1.0f / lt;
        int sr2 = q0 + rg * 16 + quad * 4 + r;
#pragma unroll
        for (int ne = 0; ne < 4; ne++)
          concat[((size_t)(b * SEQ + sr2)) * D_MODEL + h * 64 + ne * 16 + l16] = f2bf(o[rg][ne][r] * li);
      }
    }
  }
}

// ---- out = concat @ Wp^T + bp (f32 out): 128x128 tiles, BK=64,
// DOUBLE-BUFFERED (R11-verified). ----
__global__ __launch_bounds__(256) void out_gemm(const unsigned short* __restrict__ cb,
                                                const unsigned short* __restrict__ Wpb,
                                                const float* __restrict__ bp,
                                                float* __restrict__ out) {
  __shared__ unsigned short As[2][128 * 64], Bs[2][128 * 64];
  const int m0 = blockIdx.x * 128, n0 = blockIdx.y * 128;
  const int lane = threadIdx.x & 63, w = threadIdx.x >> 6;
  const int l16 = lane & 15, quad = lane >> 4;
  const int wm = w & 1, wn = w >> 1;
  const int sr = lane >> 3;
  const int scol = ((lane & 7) ^ sr) * 8;
  const unsigned short* gaA = cb + (size_t)(m0 + w * 32 + sr) * D_MODEL + scol;
  const unsigned short* gaB = Wpb + (size_t)(n0 + w * 32 + sr) * D_MODEL + scol;
  const int rswz = (l16 & 7);
  float4_t acc[4][4];
  float4_t z = {0.f, 0.f, 0.f, 0.f};
#pragma unroll
  for (int i = 0; i < 4; i++)
#pragma unroll
    for (int j = 0; j < 4; j++) acc[i][j] = z;

  auto stage = [&](int buf, int k0) {
#pragma unroll
    for (int j = 0; j < 4; j++) {
      gl_lds16(gaA + (size_t)j * 8 * D_MODEL + k0, &As[buf][(w * 32 + j * 8) * 64]);
      gl_lds16(gaB + (size_t)j * 8 * D_MODEL + k0, &Bs[buf][(w * 32 + j * 8) * 64]);
    }
  };

  stage(0, 0);
  __syncthreads();
  int cur = 0;
  for (int t = 0; t < 16; ++t) {
    if (t < 15) stage(cur ^ 1, (t + 1) * 64);
#pragma unroll
    for (int kk = 0; kk < 2; kk++) {
      const int ch = ((kk * 4 + quad) ^ rswz) * 8;
      short8 af[4], bf[4];
#pragma unroll
      for (int i = 0; i < 4; i++)
        af[i] = *(const short8*)&As[cur][(wm * 64 + i * 16 + l16) * 64 + ch];
#pragma unroll
      for (int j = 0; j < 4; j++)
        bf[j] = *(const short8*)&Bs[cur][(wn * 64 + j * 16 + l16) * 64 + ch];
#pragma unroll
      for (int i = 0; i < 4; i++)
#pragma unroll
        for (int j = 0; j < 4; j++)
          acc[i][j] = __builtin_amdgcn_mfma_f32_16x16x32_bf16(af[i], bf[j], acc[i][j], 0, 0, 0);
    }
    __syncthreads();
    cur ^= 1;
  }
#pragma unroll
  for (int i = 0; i < 4; i++)
#pragma unroll
    for (int j = 0; j < 4; j++)
#pragma unroll
      for (int r = 0; r < 4; r++) {
        int m = m0 + wm * 64 + i * 16 + quad * 4 + r;
        int oc = n0 + wn * 64 + j * 16 + l16;
        out[(size_t)m * D_MODEL + oc] = acc[i][j][r] + bp[oc];
      }
}

extern "C" void kernel_launch(void* const* d_in, const int* in_sizes, int n_in,
                              void* d_out, int out_size, void* d_ws, size_t ws_size,
                              hipStream_t stream) {
  const float* x  = (const float*)d_in[0];
  const float* Wq = (const float*)d_in[1];
  const float* Wk = (const float*)d_in[2];
  const float* Wv = (const float*)d_in[3];
  const float* bq = (const float*)d_in[4];
  const float* bk = (const float*)d_in[5];
  const float* bv = (const float*)d_in[6];
  const float* Wp = (const float*)d_in[7];
  const float* bp = (const float*)d_in[8];
  float* out = (float*)d_out;

  char* ws = (char*)d_ws;
  size_t off = 0;
  auto alloc = [&](size_t bytes) -> void* {
    void* p = ws + off;
    off += (bytes + 255) & ~(size_t)255;
    return p;
  };
  unsigned short* xb   = (unsigned short*)alloc((size_t)M_ROWS * D_MODEL * 2);
  unsigned short* Wall = (unsigned short*)alloc((size_t)NQKV * D_MODEL * 2);
  unsigned short* Wpb  = (unsigned short*)alloc((size_t)D_MODEL * D_MODEL * 2);
  unsigned short* Qb   = (unsigned short*)alloc((size_t)B_SZ * N_HEADS * SEQ * HEAD_DIM * 2);
  unsigned short* Kb   = (unsigned short*)alloc((size_t)B_SZ * N_HEADS * SEQ * HEAD_DIM * 2);
  unsigned short* Vtb  = (unsigned short*)alloc((size_t)B_SZ * N_HEADS * SEQ * HEAD_DIM * 2);
  unsigned short* cbuf = (unsigned short*)alloc((size_t)B_SZ * SEQ * D_MODEL * 2);

  prep<<<5888, 256, 0, stream>>>(x, Wp, Wq, Wk, Wv, xb, Wpb, Wall);

  qkv_gemm<<<dim3(M_ROWS / 128, NQKV / 128), 256, 0, stream>>>(xb, Wall, bq, bk, bv, Qb, Kb, Vtb);

  attn_kernel<<<256, 512, 0, stream>>>(Qb, Kb, Vtb, cbuf);

  out_gemm<<<dim3(M_ROWS / 128, D_MODEL / 128), 256, 0, stream>>>(cbuf, Wpb, bp, out);
}